// Round 9
// baseline (247.785 us; speedup 1.0000x reference)
//
#include <hip/hip_runtime.h>
#include <hip/hip_cooperative_groups.h>

namespace cg = cooperative_groups;

// LDDMM variational evolve: B=1, N=8192, D=3, fp32.
// dmom_i = 2g * (x_i * sum_j w_ij  -  sum_j w_ij x_j),  w_ij = K_ij <p_i,p_j>
// dx_i   = sum_j K_ij p_j,   K_ij = exp(-g |x_i - x_j|^2), g = 100.
//
// Round 12: single cooperative kernel. r8 settled the decomposition: partial
// ~38us (issue-bound: 44 cyc/pair = 14 VALU + v_exp, occupancy/ILP/instr
// variants all neutral), reduce ~3, finalize ~1.5, plus 2 dispatch gaps and
// the R round-trip. All 1024 partial blocks are co-resident (lb(256,4),
// 4KB LDS), so phase-fuse: partial -> grid.sync -> reduce+finalize in one
// launch. Phase 2 uses 8 lanes per point (one channel-sum per lane, shfl
// gather, lane c==0 finalizes) -- no second sync, no R buffer.
// Falls back to the proven r8 3-kernel path if cooperative launch errors.
// NOTE: ci must stay inside the exponent (arg <= 0 always); factoring
// exp2(ci) out overflows: inner arg reaches +432 -> inf * 0 = NaN.

#define TPB 256
#define ITILE 2
constexpr float GAMMA_C = 100.0f;
constexpr float LOG2E_C = 1.4426950408889634f;
constexpr float SB_C    = 2.0f * GAMMA_C * LOG2E_C;  // A.xyz = SB*x_j
constexpr float SC_C    = -GAMMA_C * LOG2E_C;        // A.w   = SC*|x_j|^2
constexpr float LN2_C   = 0.69314718055994531f;      // 2g/SB

// ---- Fused cooperative kernel ----------------------------------------------
// grid (N/(TPB*ITILE), SEG) = (16,64) = 1024 blocks, 4/CU co-resident.
// part layout: P[c][s][i], c=0..5 (wx,wy,wz,gx,gy,gz).
__global__ __launch_bounds__(TPB, 4) void lddmm_fused(
    const float* __restrict__ mom, const float* __restrict__ xpt,
    float* __restrict__ part, float* __restrict__ out,
    int N, int SEG, int JT) {
  extern __shared__ float4 smem[];
  float4* sA = smem;        // {SB*x, SB*y, SB*z, SC*|x|^2}
  float4* sP = smem + JT;   // {px, py, pz, 0}
  const int tid = threadIdx.x;
  const int seg = blockIdx.y;

  // ---------------- phase 1: per-segment partials (r8's proven loop) -------
  for (int t = tid; t < JT; t += TPB) {
    const int j = seg * JT + t;
    const float bx = xpt[3*j], by = xpt[3*j+1], bz = xpt[3*j+2];
    sA[t] = make_float4(SB_C*bx, SB_C*by, SB_C*bz,
                        SC_C * fmaf(bx, bx, fmaf(by, by, bz*bz)));
    sP[t] = make_float4(mom[3*j], mom[3*j+1], mom[3*j+2], 0.f);
  }
  __syncthreads();

  const int i0 = blockIdx.x * (TPB * ITILE) + tid;
  const int i1 = i0 + TPB;

  const float x0 = xpt[3*i0], y0 = xpt[3*i0+1], z0 = xpt[3*i0+2];
  const float p0x = mom[3*i0], p0y = mom[3*i0+1], p0z = mom[3*i0+2];
  const float c0 = SC_C * fmaf(x0, x0, fmaf(y0, y0, z0*z0));
  const float x1 = xpt[3*i1], y1 = xpt[3*i1+1], z1 = xpt[3*i1+2];
  const float p1x = mom[3*i1], p1y = mom[3*i1+1], p1z = mom[3*i1+2];
  const float c1 = SC_C * fmaf(x1, x1, fmaf(y1, y1, z1*z1));

  float wx0=0.f, wy0=0.f, wz0=0.f, gx0=0.f, gy0=0.f, gz0=0.f;
  float wx1=0.f, wy1=0.f, wz1=0.f, gx1=0.f, gy1=0.f, gz1=0.f;

#pragma unroll 4
  for (int t = 0; t < JT; ++t) {
    const float4 A = sA[t];   // broadcast (same addr all lanes): conflict-free
    const float4 P = sP[t];
    {
      const float arg = fmaf(A.x, x0, fmaf(A.y, y0, fmaf(A.z, z0, c0 + A.w)));
      const float K   = __builtin_amdgcn_exp2f(arg);          // bare v_exp_f32
      const float dot = fmaf(P.x, p0x, fmaf(P.y, p0y, P.z * p0z));
      const float w   = K * dot;
      wx0 = fmaf(w, A.x, wx0); wy0 = fmaf(w, A.y, wy0); wz0 = fmaf(w, A.z, wz0);
      gx0 = fmaf(K, P.x, gx0); gy0 = fmaf(K, P.y, gy0); gz0 = fmaf(K, P.z, gz0);
    }
    {
      const float arg = fmaf(A.x, x1, fmaf(A.y, y1, fmaf(A.z, z1, c1 + A.w)));
      const float K   = __builtin_amdgcn_exp2f(arg);
      const float dot = fmaf(P.x, p1x, fmaf(P.y, p1y, P.z * p1z));
      const float w   = K * dot;
      wx1 = fmaf(w, A.x, wx1); wy1 = fmaf(w, A.y, wy1); wz1 = fmaf(w, A.z, wz1);
      gx1 = fmaf(K, P.x, gx1); gy1 = fmaf(K, P.y, gy1); gz1 = fmaf(K, P.z, gz1);
    }
  }

  const size_t SN = (size_t)SEG * N;
  {
    float* p = part + (size_t)seg * N;
    p[0*SN+i0] = wx0; p[0*SN+i1] = wx1;
    p[1*SN+i0] = wy0; p[1*SN+i1] = wy1;
    p[2*SN+i0] = wz0; p[2*SN+i1] = wz1;
    p[3*SN+i0] = gx0; p[3*SN+i1] = gx1;
    p[4*SN+i0] = gy0; p[4*SN+i1] = gy1;
    p[5*SN+i0] = gz0; p[5*SN+i1] = gz1;
  }

  __threadfence();                 // device-scope: cross-XCD visibility
  cg::this_grid().sync();

  // ---------------- phase 2: reduce + finalize, 8 lanes per point ----------
  // gtid < 8N: lane handles (i = gtid>>3, c = gtid&7); c<6 sums its channel
  // over SEG; shfl-gather within the wave; lane c==0 writes all 6 outputs.
  const int gbid = blockIdx.y * gridDim.x + blockIdx.x;
  const int gtid = gbid * TPB + tid;
  if (gtid >= 8 * N) return;       // wave-uniform (8N multiple of 64)

  const int c  = gtid & 7;
  const int i  = gtid >> 3;
  float s = 0.f;
  if (c < 6) {
    const float* src = part + (size_t)c * SN + i;
    float s0 = 0.f, s1 = 0.f, s2 = 0.f, s3 = 0.f;
    int t = 0;
    for (; t + 4 <= SEG; t += 4) {
      s0 += src[(size_t)(t+0)*N]; s1 += src[(size_t)(t+1)*N];
      s2 += src[(size_t)(t+2)*N]; s3 += src[(size_t)(t+3)*N];
    }
    for (; t < SEG; ++t) s0 += src[(size_t)t*N];
    s = (s0 + s1) + (s2 + s3);
  }
  const int lane = tid & 63;
  const int base = lane & ~7;
  const float WX = __shfl(s, base+0, 64), WY = __shfl(s, base+1, 64);
  const float WZ = __shfl(s, base+2, 64);
  const float GX = __shfl(s, base+3, 64), GY = __shfl(s, base+4, 64);
  const float GZ = __shfl(s, base+5, 64);
  if (c == 0) {
    const float xi = xpt[3*i], yi = xpt[3*i+1], zi = xpt[3*i+2];
    const float px = mom[3*i], py = mom[3*i+1], pz = mom[3*i+2];
    const float A  = fmaf(px, GX, fmaf(py, GY, pz * GZ));   // row-sum = p.G
    const float TGA = 2.0f * GAMMA_C * A;
    out[3*i+0] = fmaf(TGA, xi, -LN2_C * WX);
    out[3*i+1] = fmaf(TGA, yi, -LN2_C * WY);
    out[3*i+2] = fmaf(TGA, zi, -LN2_C * WZ);
    out[3*N + 3*i + 0] = GX;
    out[3*N + 3*i + 1] = GY;
    out[3*N + 3*i + 2] = GZ;
  }
}

// ---- Fallback path (r8's proven 3-kernel pipeline) -------------------------
__global__ __launch_bounds__(TPB, 4) void lddmm_partial(
    const float* __restrict__ mom, const float* __restrict__ xpt,
    float* __restrict__ part, int N, int SEG, int JT) {
  extern __shared__ float4 smem[];
  float4* sA = smem;
  float4* sP = smem + JT;
  const int tid = threadIdx.x;
  const int seg = blockIdx.y;
  for (int t = tid; t < JT; t += TPB) {
    const int j = seg * JT + t;
    const float bx = xpt[3*j], by = xpt[3*j+1], bz = xpt[3*j+2];
    sA[t] = make_float4(SB_C*bx, SB_C*by, SB_C*bz,
                        SC_C * fmaf(bx, bx, fmaf(by, by, bz*bz)));
    sP[t] = make_float4(mom[3*j], mom[3*j+1], mom[3*j+2], 0.f);
  }
  __syncthreads();
  const int i0 = blockIdx.x * (TPB * ITILE) + tid;
  const int i1 = i0 + TPB;
  const float x0 = xpt[3*i0], y0 = xpt[3*i0+1], z0 = xpt[3*i0+2];
  const float p0x = mom[3*i0], p0y = mom[3*i0+1], p0z = mom[3*i0+2];
  const float c0 = SC_C * fmaf(x0, x0, fmaf(y0, y0, z0*z0));
  const float x1 = xpt[3*i1], y1 = xpt[3*i1+1], z1 = xpt[3*i1+2];
  const float p1x = mom[3*i1], p1y = mom[3*i1+1], p1z = mom[3*i1+2];
  const float c1 = SC_C * fmaf(x1, x1, fmaf(y1, y1, z1*z1));
  float wx0=0.f, wy0=0.f, wz0=0.f, gx0=0.f, gy0=0.f, gz0=0.f;
  float wx1=0.f, wy1=0.f, wz1=0.f, gx1=0.f, gy1=0.f, gz1=0.f;
#pragma unroll 4
  for (int t = 0; t < JT; ++t) {
    const float4 A = sA[t];
    const float4 P = sP[t];
    {
      const float arg = fmaf(A.x, x0, fmaf(A.y, y0, fmaf(A.z, z0, c0 + A.w)));
      const float K   = __builtin_amdgcn_exp2f(arg);
      const float dot = fmaf(P.x, p0x, fmaf(P.y, p0y, P.z * p0z));
      const float w   = K * dot;
      wx0 = fmaf(w, A.x, wx0); wy0 = fmaf(w, A.y, wy0); wz0 = fmaf(w, A.z, wz0);
      gx0 = fmaf(K, P.x, gx0); gy0 = fmaf(K, P.y, gy0); gz0 = fmaf(K, P.z, gz0);
    }
    {
      const float arg = fmaf(A.x, x1, fmaf(A.y, y1, fmaf(A.z, z1, c1 + A.w)));
      const float K   = __builtin_amdgcn_exp2f(arg);
      const float dot = fmaf(P.x, p1x, fmaf(P.y, p1y, P.z * p1z));
      const float w   = K * dot;
      wx1 = fmaf(w, A.x, wx1); wy1 = fmaf(w, A.y, wy1); wz1 = fmaf(w, A.z, wz1);
      gx1 = fmaf(K, P.x, gx1); gy1 = fmaf(K, P.y, gy1); gz1 = fmaf(K, P.z, gz1);
    }
  }
  const size_t SN = (size_t)SEG * N;
  float* p = part + (size_t)seg * N;
  p[0*SN+i0] = wx0; p[0*SN+i1] = wx1;
  p[1*SN+i0] = wy0; p[1*SN+i1] = wy1;
  p[2*SN+i0] = wz0; p[2*SN+i1] = wz1;
  p[3*SN+i0] = gx0; p[3*SN+i1] = gx1;
  p[4*SN+i0] = gy0; p[4*SN+i1] = gy1;
  p[5*SN+i0] = gz0; p[5*SN+i1] = gz1;
}

__global__ __launch_bounds__(TPB) void lddmm_reduce(
    const float* __restrict__ part, float* __restrict__ R, int N, int SEG) {
  const int i = blockIdx.x * TPB + threadIdx.x;
  const int c = blockIdx.y;
  const float* src = part + (size_t)c * SEG * N + i;
  float s0 = 0.f, s1 = 0.f, s2 = 0.f, s3 = 0.f;
  int s = 0;
  for (; s + 4 <= SEG; s += 4) {
    s0 += src[(size_t)(s+0)*N]; s1 += src[(size_t)(s+1)*N];
    s2 += src[(size_t)(s+2)*N]; s3 += src[(size_t)(s+3)*N];
  }
  for (; s < SEG; ++s) s0 += src[(size_t)s*N];
  R[(size_t)c * N + i] = (s0 + s1) + (s2 + s3);
}

__global__ __launch_bounds__(TPB) void lddmm_finalize(
    const float* __restrict__ R, const float* __restrict__ xpt,
    const float* __restrict__ mom, float* __restrict__ out, int N) {
  const int i = blockIdx.x * TPB + threadIdx.x;
  const float WX = R[(size_t)0*N+i], WY = R[(size_t)1*N+i], WZ = R[(size_t)2*N+i];
  const float GX = R[(size_t)3*N+i], GY = R[(size_t)4*N+i], GZ = R[(size_t)5*N+i];
  const float xi = xpt[3*i], yi = xpt[3*i+1], zi = xpt[3*i+2];
  const float px = mom[3*i], py = mom[3*i+1], pz = mom[3*i+2];
  const float A  = fmaf(px, GX, fmaf(py, GY, pz * GZ));
  const float TGA = 2.0f * GAMMA_C * A;
  out[3*i+0] = fmaf(TGA, xi, -LN2_C * WX);
  out[3*i+1] = fmaf(TGA, yi, -LN2_C * WY);
  out[3*i+2] = fmaf(TGA, zi, -LN2_C * WZ);
  out[3*N + 3*i + 0] = GX;
  out[3*N + 3*i + 1] = GY;
  out[3*N + 3*i + 2] = GZ;
}

// ---- Fallback (tiny ws): atomic single-kernel version ----------------------
__global__ __launch_bounds__(TPB) void lddmm_atomic(
    const float* __restrict__ mom, const float* __restrict__ xpt,
    float* __restrict__ out, int N) {
  const int i  = blockIdx.x * TPB + threadIdx.x;
  const int jb = blockIdx.y * TPB;
  __shared__ float4 sA[TPB], sP[TPB];
  {
    const int j = jb + threadIdx.x;
    const float bx = xpt[3*j], by = xpt[3*j+1], bz = xpt[3*j+2];
    sA[threadIdx.x] = make_float4(SB_C*bx, SB_C*by, SB_C*bz,
                                  SC_C * fmaf(bx, bx, fmaf(by, by, bz*bz)));
    sP[threadIdx.x] = make_float4(mom[3*j], mom[3*j+1], mom[3*j+2], 0.f);
  }
  __syncthreads();
  const float xi = xpt[3*i], yi = xpt[3*i+1], zi = xpt[3*i+2];
  const float pxi = mom[3*i], pyi = mom[3*i+1], pzi = mom[3*i+2];
  const float ci = SC_C * fmaf(xi, xi, fmaf(yi, yi, zi*zi));
  float a=0.f, wx=0.f, wy=0.f, wz=0.f, gx=0.f, gy=0.f, gz=0.f;
#pragma unroll 4
  for (int t = 0; t < TPB; ++t) {
    const float4 A = sA[t], P = sP[t];
    const float arg = fmaf(A.x, xi, fmaf(A.y, yi, fmaf(A.z, zi, ci + A.w)));
    const float K   = __builtin_amdgcn_exp2f(arg);
    const float dot = fmaf(P.x, pxi, fmaf(P.y, pyi, P.z * pzi));
    const float w   = K * dot;
    a += w;
    wx = fmaf(w, A.x, wx); wy = fmaf(w, A.y, wy); wz = fmaf(w, A.z, wz);
    gx = fmaf(K, P.x, gx); gy = fmaf(K, P.y, gy); gz = fmaf(K, P.z, gz);
  }
  const float TGA = 2.0f * GAMMA_C * a;
  atomicAdd(&out[3*i+0], fmaf(TGA, xi, -LN2_C * wx));
  atomicAdd(&out[3*i+1], fmaf(TGA, yi, -LN2_C * wy));
  atomicAdd(&out[3*i+2], fmaf(TGA, zi, -LN2_C * wz));
  atomicAdd(&out[3*N+3*i+0], gx);
  atomicAdd(&out[3*N+3*i+1], gy);
  atomicAdd(&out[3*N+3*i+2], gz);
}

extern "C" void kernel_launch(void* const* d_in, const int* in_sizes, int n_in,
                              void* d_out, int out_size, void* d_ws, size_t ws_size,
                              hipStream_t stream) {
  const float* mom = (const float*)d_in[0];   // setup_inputs order: mom first
  const float* xpt = (const float*)d_in[1];   // control_points second
  float* out = (float*)d_out;
  const int N = in_sizes[0] / 3;              // 8192

  // ws layout: part (6*SEG*N floats) | R (6*N floats, fallback only)
  auto need = [&](int s) { return (size_t)(6*s + 6) * (size_t)N * sizeof(float); };
  int SEG = 64;                               // 12.6 MB partials
  while (SEG > 2 && need(SEG) > ws_size) SEG >>= 1;

  const bool shapes_ok = (N % (TPB * ITILE) == 0) && (N % SEG == 0) &&
                         (N % TPB == 0) && ((8 * N) % 64 == 0) &&
                         (SEG >= 8 * ITILE);
  if (need(SEG) <= ws_size && shapes_ok) {
    int JT = N / SEG;                         // 128 @ SEG=64
    float* partb = (float*)d_ws;
    float* R     = partb + (size_t)6 * SEG * N;
    const size_t shmem = (size_t)JT * 2 * sizeof(float4);   // 4 KB @ JT=128
    dim3 gA(N / (TPB * ITILE), SEG);          // (16, 64) = 1024 blocks, 4/CU

    int Nv = N, SEGv = SEG, JTv = JT;
    void* args[] = { (void*)&mom, (void*)&xpt, (void*)&partb, (void*)&out,
                     (void*)&Nv, (void*)&SEGv, (void*)&JTv };
    hipError_t e = hipLaunchCooperativeKernel((const void*)lddmm_fused,
                                              gA, dim3(TPB), args,
                                              (unsigned int)shmem, stream);
    if (e != hipSuccess) {
      (void)hipGetLastError();                // clear sticky error
      lddmm_partial<<<gA, TPB, shmem, stream>>>(mom, xpt, partb, N, SEG, JT);
      dim3 gB(N / TPB, 6);
      lddmm_reduce<<<gB, TPB, 0, stream>>>(partb, R, N, SEG);
      lddmm_finalize<<<N / TPB, TPB, 0, stream>>>(R, xpt, mom, out, N);
    }
  } else {
    hipMemsetAsync(d_out, 0, (size_t)out_size * sizeof(float), stream);
    dim3 grid(N / TPB, N / TPB);
    lddmm_atomic<<<grid, TPB, 0, stream>>>(mom, xpt, out, N);
  }
}

// Round 10
// 93.542 us; speedup vs baseline: 2.6489x; 2.6489x over previous
//
#include <hip/hip_runtime.h>

// LDDMM variational evolve: B=1, N=8192, D=3, fp32.
// dmom_i = 2g * (x_i * sum_j w_ij  -  sum_j w_ij x_j),  w_ij = K_ij <p_i,p_j>
// dx_i   = sum_j K_ij p_j,   K_ij = exp(-g |x_i - x_j|^2), g = 100.
//
// Round 13: r9 refuted cooperative fusion (grid.sync ~140us on MI355X: 1024
// blocks spinning on device atomics across 8 non-coherent XCDs; fused kernel
// 182us @ VALUBusy 15%). Reverted to r8's proven pipeline (94.9us best) with
// ONE change: reduce+finalize merged into a single kernel reusing r9's
// correctness-proven phase-2 scheme (8 lanes/point: lane c sums channel c
// over SEG, shfl-gather, lane 0 writes outputs). Grid 8N/256 = 256 blocks =
// 1/CU over 12.6MB -> ~3-4us; kills one dispatch gap + the R round-trip.
// Ledger: j-loop is pipe-saturated at 44cyc/pair (r5 PMC: VALUBusy 67% =
// 28 busy fma cyc / 44, exp counts as non-busy); pk-fp32 rate-neutral (r4 +
// 157.3TF spec arithmetic); occupancy/ILP neutral (r2/r3/r7); lb(512,8)
// spills (r6); coop sync catastrophic (r9).
// NOTE: ci must stay inside the exponent (arg <= 0 always); factoring
// exp2(ci) out overflows: inner arg reaches +432 -> inf * 0 = NaN.

#define TPB 256
#define ITILE 2
constexpr float GAMMA_C = 100.0f;
constexpr float LOG2E_C = 1.4426950408889634f;
constexpr float SB_C    = 2.0f * GAMMA_C * LOG2E_C;  // A.xyz = SB*x_j
constexpr float SC_C    = -GAMMA_C * LOG2E_C;        // A.w   = SC*|x_j|^2
constexpr float LN2_C   = 0.69314718055994531f;      // 2g/SB

// ---- Kernel A: per-segment partial sums (r8 verbatim) ----------------------
// grid (N/(TPB*ITILE), SEG). part layout: P[c][s][i], c=0..5 (wx,wy,wz,gx,gy,gz).
__global__ __launch_bounds__(TPB, 4) void lddmm_partial(
    const float* __restrict__ mom, const float* __restrict__ xpt,
    float* __restrict__ part, int N, int SEG, int JT) {
  extern __shared__ float4 smem[];
  float4* sA = smem;        // {SB*x, SB*y, SB*z, SC*|x|^2}
  float4* sP = smem + JT;   // {px, py, pz, 0}
  const int tid = threadIdx.x;
  const int seg = blockIdx.y;

  for (int t = tid; t < JT; t += TPB) {
    const int j = seg * JT + t;
    const float bx = xpt[3*j], by = xpt[3*j+1], bz = xpt[3*j+2];
    sA[t] = make_float4(SB_C*bx, SB_C*by, SB_C*bz,
                        SC_C * fmaf(bx, bx, fmaf(by, by, bz*bz)));
    sP[t] = make_float4(mom[3*j], mom[3*j+1], mom[3*j+2], 0.f);
  }
  __syncthreads();

  const int i0 = blockIdx.x * (TPB * ITILE) + tid;
  const int i1 = i0 + TPB;

  const float x0 = xpt[3*i0], y0 = xpt[3*i0+1], z0 = xpt[3*i0+2];
  const float p0x = mom[3*i0], p0y = mom[3*i0+1], p0z = mom[3*i0+2];
  const float c0 = SC_C * fmaf(x0, x0, fmaf(y0, y0, z0*z0));
  const float x1 = xpt[3*i1], y1 = xpt[3*i1+1], z1 = xpt[3*i1+2];
  const float p1x = mom[3*i1], p1y = mom[3*i1+1], p1z = mom[3*i1+2];
  const float c1 = SC_C * fmaf(x1, x1, fmaf(y1, y1, z1*z1));

  float wx0=0.f, wy0=0.f, wz0=0.f, gx0=0.f, gy0=0.f, gz0=0.f;
  float wx1=0.f, wy1=0.f, wz1=0.f, gx1=0.f, gy1=0.f, gz1=0.f;

#pragma unroll 4
  for (int t = 0; t < JT; ++t) {
    const float4 A = sA[t];   // broadcast (same addr all lanes): conflict-free
    const float4 P = sP[t];
    // i0  (14 VALU + 1 exp; row-sum dropped, A_i recovered as p_i.G_i)
    {
      const float arg = fmaf(A.x, x0, fmaf(A.y, y0, fmaf(A.z, z0, c0 + A.w)));
      const float K   = __builtin_amdgcn_exp2f(arg);          // bare v_exp_f32
      const float dot = fmaf(P.x, p0x, fmaf(P.y, p0y, P.z * p0z));
      const float w   = K * dot;
      wx0 = fmaf(w, A.x, wx0); wy0 = fmaf(w, A.y, wy0); wz0 = fmaf(w, A.z, wz0);
      gx0 = fmaf(K, P.x, gx0); gy0 = fmaf(K, P.y, gy0); gz0 = fmaf(K, P.z, gz0);
    }
    // i1
    {
      const float arg = fmaf(A.x, x1, fmaf(A.y, y1, fmaf(A.z, z1, c1 + A.w)));
      const float K   = __builtin_amdgcn_exp2f(arg);
      const float dot = fmaf(P.x, p1x, fmaf(P.y, p1y, P.z * p1z));
      const float w   = K * dot;
      wx1 = fmaf(w, A.x, wx1); wy1 = fmaf(w, A.y, wy1); wz1 = fmaf(w, A.z, wz1);
      gx1 = fmaf(K, P.x, gx1); gy1 = fmaf(K, P.y, gy1); gz1 = fmaf(K, P.z, gz1);
    }
  }

  const size_t SN = (size_t)SEG * N;
  float* p = part + (size_t)seg * N;
  p[0*SN+i0] = wx0; p[0*SN+i1] = wx1;
  p[1*SN+i0] = wy0; p[1*SN+i1] = wy1;
  p[2*SN+i0] = wz0; p[2*SN+i1] = wz1;
  p[3*SN+i0] = gx0; p[3*SN+i1] = gx1;
  p[4*SN+i0] = gy0; p[4*SN+i1] = gy1;
  p[5*SN+i0] = gz0; p[5*SN+i1] = gz1;
}

// ---- Kernel B: merged reduce + finalize ------------------------------------
// 8 lanes per point: lane c (of 8) sums channel c over SEG (c<6 active),
// shfl-gather the 6 sums within the aligned 8-lane group, lane 0 finalizes.
// grid = 8N/TPB = 256 blocks (1/CU over 12.6 MB -> BW-parallel, ~3-4us).
__global__ __launch_bounds__(TPB) void lddmm_reduce_fin(
    const float* __restrict__ part, const float* __restrict__ xpt,
    const float* __restrict__ mom, float* __restrict__ out, int N, int SEG) {
  const int gtid = blockIdx.x * TPB + threadIdx.x;
  if (gtid >= 8 * N) return;       // wave-uniform (8N multiple of 64)
  const int c = gtid & 7;
  const int i = gtid >> 3;
  const size_t SN = (size_t)SEG * N;

  float s = 0.f;
  if (c < 6) {
    const float* src = part + (size_t)c * SN + i;
    float s0 = 0.f, s1 = 0.f, s2 = 0.f, s3 = 0.f;
    int t = 0;
    for (; t + 4 <= SEG; t += 4) {
      s0 += src[(size_t)(t+0)*N]; s1 += src[(size_t)(t+1)*N];
      s2 += src[(size_t)(t+2)*N]; s3 += src[(size_t)(t+3)*N];
    }
    for (; t < SEG; ++t) s0 += src[(size_t)t*N];
    s = (s0 + s1) + (s2 + s3);
  }
  const int lane = threadIdx.x & 63;
  const int base = lane & ~7;
  const float WX = __shfl(s, base+0, 64), WY = __shfl(s, base+1, 64);
  const float WZ = __shfl(s, base+2, 64);
  const float GX = __shfl(s, base+3, 64), GY = __shfl(s, base+4, 64);
  const float GZ = __shfl(s, base+5, 64);
  if (c == 0) {
    const float xi = xpt[3*i], yi = xpt[3*i+1], zi = xpt[3*i+2];
    const float px = mom[3*i], py = mom[3*i+1], pz = mom[3*i+2];
    const float A  = fmaf(px, GX, fmaf(py, GY, pz * GZ));   // row-sum = p.G
    const float TGA = 2.0f * GAMMA_C * A;
    out[3*i+0] = fmaf(TGA, xi, -LN2_C * WX);
    out[3*i+1] = fmaf(TGA, yi, -LN2_C * WY);
    out[3*i+2] = fmaf(TGA, zi, -LN2_C * WZ);
    out[3*N + 3*i + 0] = GX;
    out[3*N + 3*i + 1] = GY;
    out[3*N + 3*i + 2] = GZ;
  }
}

// ---- Fallback (tiny ws): atomic single-kernel version ----------------------
__global__ __launch_bounds__(TPB) void lddmm_atomic(
    const float* __restrict__ mom, const float* __restrict__ xpt,
    float* __restrict__ out, int N) {
  const int i  = blockIdx.x * TPB + threadIdx.x;
  const int jb = blockIdx.y * TPB;
  __shared__ float4 sA[TPB], sP[TPB];
  {
    const int j = jb + threadIdx.x;
    const float bx = xpt[3*j], by = xpt[3*j+1], bz = xpt[3*j+2];
    sA[threadIdx.x] = make_float4(SB_C*bx, SB_C*by, SB_C*bz,
                                  SC_C * fmaf(bx, bx, fmaf(by, by, bz*bz)));
    sP[threadIdx.x] = make_float4(mom[3*j], mom[3*j+1], mom[3*j+2], 0.f);
  }
  __syncthreads();
  const float xi = xpt[3*i], yi = xpt[3*i+1], zi = xpt[3*i+2];
  const float pxi = mom[3*i], pyi = mom[3*i+1], pzi = mom[3*i+2];
  const float ci = SC_C * fmaf(xi, xi, fmaf(yi, yi, zi*zi));
  float a=0.f, wx=0.f, wy=0.f, wz=0.f, gx=0.f, gy=0.f, gz=0.f;
#pragma unroll 4
  for (int t = 0; t < TPB; ++t) {
    const float4 A = sA[t], P = sP[t];
    const float arg = fmaf(A.x, xi, fmaf(A.y, yi, fmaf(A.z, zi, ci + A.w)));
    const float K   = __builtin_amdgcn_exp2f(arg);
    const float dot = fmaf(P.x, pxi, fmaf(P.y, pyi, P.z * pzi));
    const float w   = K * dot;
    a += w;
    wx = fmaf(w, A.x, wx); wy = fmaf(w, A.y, wy); wz = fmaf(w, A.z, wz);
    gx = fmaf(K, P.x, gx); gy = fmaf(K, P.y, gy); gz = fmaf(K, P.z, gz);
  }
  const float TGA = 2.0f * GAMMA_C * a;
  atomicAdd(&out[3*i+0], fmaf(TGA, xi, -LN2_C * wx));
  atomicAdd(&out[3*i+1], fmaf(TGA, yi, -LN2_C * wy));
  atomicAdd(&out[3*i+2], fmaf(TGA, zi, -LN2_C * wz));
  atomicAdd(&out[3*N+3*i+0], gx);
  atomicAdd(&out[3*N+3*i+1], gy);
  atomicAdd(&out[3*N+3*i+2], gz);
}

extern "C" void kernel_launch(void* const* d_in, const int* in_sizes, int n_in,
                              void* d_out, int out_size, void* d_ws, size_t ws_size,
                              hipStream_t stream) {
  const float* mom = (const float*)d_in[0];   // setup_inputs order: mom first
  const float* xpt = (const float*)d_in[1];   // control_points second
  float* out = (float*)d_out;
  const int N = in_sizes[0] / 3;              // 8192

  // ws layout: part (6*SEG*N floats)
  auto need = [&](int s) { return (size_t)(6*s) * (size_t)N * sizeof(float); };
  int SEG = 64;                               // 12.6 MB partials
  while (SEG > 2 && need(SEG) > ws_size) SEG >>= 1;

  const bool shapes_ok = (N % (TPB * ITILE) == 0) && (N % SEG == 0) &&
                         ((8 * N) % TPB == 0) && (SEG % 4 == 0) &&
                         ((N / SEG) <= TPB);
  if (need(SEG) <= ws_size && shapes_ok) {
    const int JT = N / SEG;                   // 128 @ SEG=64
    float* partb = (float*)d_ws;
    const size_t shmem = (size_t)JT * 2 * sizeof(float4);   // 4 KB @ JT=128
    dim3 gA(N / (TPB * ITILE), SEG);          // (16, 64) = 1024 blocks, 4/CU
    lddmm_partial<<<gA, TPB, shmem, stream>>>(mom, xpt, partb, N, SEG, JT);
    lddmm_reduce_fin<<<(8 * N) / TPB, TPB, 0, stream>>>(partb, xpt, mom, out,
                                                        N, SEG);
  } else {
    hipMemsetAsync(d_out, 0, (size_t)out_size * sizeof(float), stream);
    dim3 grid(N / TPB, N / TPB);
    lddmm_atomic<<<grid, TPB, 0, stream>>>(mom, xpt, out, N);
  }
}